// Round 4
// baseline (353.744 us; speedup 1.0000x reference)
//
#include <hip/hip_runtime.h>

// Problem constants (from reference)
#define IN_FEATURES 4096
#define RANK 64
#define NUM_EXPERTS 8
#define KDIM 512          // NUM_EXPERTS * RANK (GEMM K)
#define TOKENS 16384      // B*S = 4*4096      (GEMM M)
#define SCALING 1.0f      // ALPHA / RANK = 64/64

// 256x128 tile, BK=32, 2 blocks/CU co-residency (48 KiB LDS, VGPR<=128).
#define BM 256
#define BN 128
#define BK 32
#define NKT (KDIM / BK)   // 16 K-tiles

typedef __bf16 bf16x8 __attribute__((ext_vector_type(8)));
typedef float f32x4 __attribute__((ext_vector_type(4)));

__device__ __forceinline__ unsigned short f2bf(float f) {
  union { float f; unsigned int u; } v; v.f = f;
  unsigned int u = v.u;
  u += 0x7fffu + ((u >> 16) & 1u);   // round-to-nearest-even
  return (unsigned short)(u >> 16);
}

__device__ __forceinline__ void gload_lds16(const unsigned short* g, unsigned short* l) {
  __builtin_amdgcn_global_load_lds(
      (const __attribute__((address_space(1))) void*)g,
      (__attribute__((address_space(3))) void*)l,
      16, 0, 0);
}

// Bt[d, k*RANK+r] = bf16(A[k,d,r] * mask[k,d,r] * SCALING). 4 bf16/thread.
#define BN4 ((long)IN_FEATURES * KDIM / 4)   // 524,288 threads
__global__ void __launch_bounds__(256) b_pack(
    const float* __restrict__ A, const float* __restrict__ mask,
    unsigned short* __restrict__ Bt) {
  int idx = blockIdx.x * 256 + threadIdx.x;   // d*128 + k*16 + r4
  int d = idx >> 7;
  int k = (idx >> 4) & 7;
  int r0 = (idx & 15) * 4;
  long src = ((long)k * IN_FEATURES + d) * RANK + r0;
  float4 a = *(const float4*)&A[src];
  float4 m = *(const float4*)&mask[src];
  ushort4 o;
  o.x = f2bf(a.x * m.x * SCALING);
  o.y = f2bf(a.y * m.y * SCALING);
  o.z = f2bf(a.z * m.z * SCALING);
  o.w = f2bf(a.w * m.w * SCALING);
  *(ushort4*)&Bt[(long)d * KDIM + k * RANK + r0] = o;
}

// out[M,N] = (w ⊙k p)[M,K] @ Bt[N,K]^T with the A-operand FUSED: the q
// workspace is gone. For K-tile kt (expert e=kt>>1, rank base rb=(kt&1)*32),
// A[t, kc*8..+7] = bf16(w[t,e] * p[t, rb+kc*8..+7]) is computed in-register
// (4x float4 p loads + 2 scalar w + 16 mul + 16 cvt per thread) and written
// with ds_write_b128 directly into the swizzled LDS layout the read path
// expects (slot c holds logical kc=(c&3)^((row>>1)&3); row=c>>2).
// T14 split: p-loads + B global_load_lds issue at the TOP of the K-step;
// cvt+ds_write land AFTER the MFMAs (latency hidden under compute);
// one __syncthreads per K-step covers vmcnt+lgkm and buffer swap (dbuf).
// B-side unchanged: packed Bt staged via global_load_lds, pre-swizzled src.
// 8 waves (2M x 4N), per-wave 128x32 = acc[8][2] f32x4. 2 blocks/CU.
// GRID M-MAJOR: XCD = linear_id%8 = blockIdx.x%8, so all N-blocks sharing
// a p/w panel land on one XCD's L2.
__global__ void __launch_bounds__(512, 4) gemm_kernel(
    const float* __restrict__ p,            // [TOKENS, RANK]
    const float* __restrict__ w,            // [TOKENS, NUM_EXPERTS]
    const unsigned short* __restrict__ Bt,  // [IN_FEATURES, KDIM]
    float* __restrict__ out) {              // [TOKENS, IN_FEATURES]
  __shared__ __align__(16) unsigned short sA[2][BM * BK];  // 32 KiB
  __shared__ __align__(16) unsigned short sB[2][BN * BK];  // 16 KiB

  const int tid = threadIdx.x;
  const int lane = tid & 63;
  const int wid = tid >> 6;
  const int u = lane & 15;        // fragment row-within-16 / C col
  const int quad = lane >> 4;     // k-chunk select / C row group
  const int wave_m = (wid >> 2) * 128;
  const int wave_n = (wid & 3) * 32;

  const int m0 = blockIdx.x * BM;   // M-major grid
  const int n0 = blockIdx.y * BN;

  f32x4 acc[8][2];
#pragma unroll
  for (int i = 0; i < 8; ++i)
#pragma unroll
    for (int j = 0; j < 2; ++j)
      acc[i][j] = (f32x4){0.f, 0.f, 0.f, 0.f};

  // A-tile: 256 rows x 4 chunks = 1024 chunks; thread stages c0=tid, c1=tid+512.
  // B-tile: 512 chunks, 1/thread, staged via gload_lds with pre-swizzled src.
  const int cA0 = tid, cA1 = tid + 512, cB = tid;
  const int rA0 = cA0 >> 2, rA1 = cA1 >> 2, rBr = cB >> 2;
  const int lgA0 = (cA0 & 3) ^ ((rA0 >> 1) & 3);
  const int lgA1 = (cA1 & 3) ^ ((rA1 >> 1) & 3);
  const int lgB  = (cB  & 3) ^ ((rBr >> 1) & 3);
  const float* pR0 = p + (m0 + rA0) * RANK + lgA0 * 8;  // + rb for K-tile
  const float* pR1 = p + (m0 + rA1) * RANK + lgA1 * 8;
  const float* wR0 = w + (m0 + rA0) * NUM_EXPERTS;      // [e]
  const float* wR1 = w + (m0 + rA1) * NUM_EXPERTS;
  const unsigned short* gB = Bt + (n0 + rBr) * KDIM + lgB * 8;
  const int lA0 = cA0 * 8, lA1 = cA1 * 8, lB = cB * 8;

  auto stageB = [&](int buf, int kt) {
    gload_lds16(gB + (kt & (NKT - 1)) * BK, &sB[buf][lB]);
  };
  // Load the fused-A inputs for K-tile kt (8 p-floats + 1 w per chunk).
  auto loadA = [&](int kt, f32x4 (&pv)[2][2], float (&wv)[2]) {
    int kw = kt & (NKT - 1);
    int rb = (kw & 1) * BK;     // rank base within p row
    int e  = kw >> 1;           // expert
    pv[0][0] = *(const f32x4*)(pR0 + rb);
    pv[0][1] = *(const f32x4*)(pR0 + rb + 4);
    pv[1][0] = *(const f32x4*)(pR1 + rb);
    pv[1][1] = *(const f32x4*)(pR1 + rb + 4);
    wv[0] = wR0[e];
    wv[1] = wR1[e];
  };
  auto writeA = [&](int buf, f32x4 (&pv)[2][2], float (&wv)[2]) {
    unsigned short tmp[2][8];
#pragma unroll
    for (int h = 0; h < 2; ++h)
#pragma unroll
      for (int j = 0; j < 2; ++j)
#pragma unroll
        for (int x = 0; x < 4; ++x)
          tmp[h][j * 4 + x] = f2bf(wv[h] * pv[h][j][x]);
    *(bf16x8*)&sA[buf][lA0] = *(bf16x8*)tmp[0];
    *(bf16x8*)&sA[buf][lA1] = *(bf16x8*)tmp[1];
  };

  const int physv = quad ^ ((u >> 1) & 3);   // swizzled k-chunk slot for reads

  // Prologue: fill buf0 with kt0.
  {
    f32x4 pv[2][2]; float wv[2];
    stageB(0, 0);
    loadA(0, pv, wv);
    writeA(0, pv, wv);
  }
  __syncthreads();

  for (int kt = 0; kt < NKT; ++kt) {
    const int buf = kt & 1;
    // Issue next-tile global ops early (B direct-to-LDS; A into regs).
    stageB(buf ^ 1, kt + 1);
    f32x4 pv[2][2]; float wv[2];
    loadA(kt + 1, pv, wv);   // last iter: wrapped kt0, staged dead

    const unsigned short* bA = sA[buf];
    const unsigned short* bB = sB[buf];

    bf16x8 bfr[2];
#pragma unroll
    for (int g = 0; g < 2; ++g) {
      int r = wave_n + g * 16 + u;
      bfr[g] = *(const bf16x8*)&bB[r * BK + physv * 8];
    }
#pragma unroll
    for (int h = 0; h < 2; ++h) {
      bf16x8 af[4];
#pragma unroll
      for (int f = 0; f < 4; ++f) {
        int r = wave_m + (h * 4 + f) * 16 + u;
        af[f] = *(const bf16x8*)&bA[r * BK + physv * 8];
      }
#pragma unroll
      for (int f = 0; f < 4; ++f)
#pragma unroll
        for (int g = 0; g < 2; ++g)
          acc[h * 4 + f][g] = __builtin_amdgcn_mfma_f32_16x16x32_bf16(
              af[f], bfr[g], acc[h * 4 + f][g], 0, 0, 0);
    }

    // Late A-write into the other buffer (hidden under the MFMAs above).
    writeA(buf ^ 1, pv, wv);
    __syncthreads();   // drains lgkm + vmcnt; both buffers consistent
  }

  // Epilogue: C/D layout col = lane&15, row = quad*4 + reg
#pragma unroll
  for (int f = 0; f < 8; ++f) {
    int row = m0 + wave_m + f * 16 + quad * 4;
#pragma unroll
    for (int rr = 0; rr < 4; ++rr) {
      float* orow = out + (long)(row + rr) * IN_FEATURES + n0 + wave_n + u;
#pragma unroll
      for (int g = 0; g < 2; ++g)
        orow[g * 16] = acc[f][g][rr];
    }
  }
}

extern "C" void kernel_launch(void* const* d_in, const int* in_sizes, int n_in,
                              void* d_out, int out_size, void* d_ws, size_t ws_size,
                              hipStream_t stream) {
  const float* p    = (const float*)d_in[0];  // [4,4096,64]
  const float* w    = (const float*)d_in[1];  // [4,4096,8]
  const float* A    = (const float*)d_in[2];  // [8,4096,64]
  const float* mask = (const float*)d_in[3];  // [8,4096,64]
  float* out = (float*)d_out;                 // [4,4096,4096]

  unsigned short* Bt = (unsigned short*)d_ws; // 4 MiB bf16 [IN_FEATURES, KDIM]

  b_pack<<<(int)(BN4 / 256), 256, 0, stream>>>(A, mask, Bt);

  dim3 grid(TOKENS / BM, IN_FEATURES / BN);   // (64, 32) M-major
  gemm_kernel<<<grid, dim3(512), 0, stream>>>(p, w, Bt, out);
}